// Round 6
// baseline (988.199 us; speedup 1.0000x reference)
//
#include <hip/hip_runtime.h>

namespace {

constexpr int T_LEN = 2048;
constexpr int B_TOT = 2048;
constexpr int H1 = 36;      // layer-1 units; lane 36 = layer-2 LSTM
constexpr int WPB = 4;      // waves (=batches) per block
constexpr int BLOCK = 64 * WPB;
constexpr int LDSW = 128;   // _Float16 slots per wave region: h[64] + relu[64]

typedef _Float16 h16x2 __attribute__((ext_vector_type(2)));

__device__ __forceinline__ float fdot2(float wb, float hb, float acc) {
#if __has_builtin(__builtin_amdgcn_fdot2)
  return __builtin_amdgcn_fdot2(__builtin_bit_cast(h16x2, wb),
                                __builtin_bit_cast(h16x2, hb), acc, false);
#else
  float d;
  asm("v_dot2_f32_f16 %0, %1, %2, %3"
      : "=v"(d) : "v"(wb), "v"(hb), "0"(acc));  // tied acc: no marshalling mov
  return d;
#endif
}

__device__ __forceinline__ float pack2h(float a, float b) {
  h16x2 t = {(_Float16)a, (_Float16)b};
  return __builtin_bit_cast(float, t);
}

__device__ __forceinline__ float fexp2(float x) { return __builtin_amdgcn_exp2f(x); }
__device__ __forceinline__ float frcp(float x) { return __builtin_amdgcn_rcpf(x); }
__device__ __forceinline__ float sigm(float x) { return frcp(1.f + fexp2(x * -1.44269504f)); }
__device__ __forceinline__ float tanh_fast(float x) {
  return fmaf(2.f, frcp(1.f + fexp2(x * -2.88539008f)), -1.f);  // 2*sigm(2x)-1
}

// waves_per_eu(2,2): pin exactly 2 waves/EU (matches grid: 2 blocks/CU x 4 waves
// = 8 waves/CU = 2/SIMD). Gives the allocator the full 256-reg arch budget so
// the 72 resident weight dwords stay in arch VGPRs -- no AGPR park + accvgpr_read
// marshalling around the VOP3P dot2s (round-5 diagnosis: VGPR_Count=76).
__global__ __launch_bounds__(BLOCK)
__attribute__((amdgpu_waves_per_eu(2, 2))) void lstm2_kernel(
    const float* __restrict__ x, const float* __restrict__ Wih1,
    const float* __restrict__ Whh1, const float* __restrict__ bih1,
    const float* __restrict__ bhh1, const float* __restrict__ Wih2,
    const float* __restrict__ Whh2, const float* __restrict__ bih2,
    const float* __restrict__ bhh2, float* __restrict__ out)
{
  __shared__ __align__(16) _Float16 sh[WPB * LDSW];

  const int tid = threadIdx.x;
  const int w = tid >> 6;
  const int lane = tid & 63;
  const int batch = blockIdx.x * WPB + w;

  _Float16* hh = sh + w * LDSW;  // h1 (fp16), slots 0..35 live, 36..63 dump
  _Float16* hr = hh + 64;        // relu(h1) (fp16) for the L2 lane

  const bool isA = lane < H1;
  const bool isL2 = lane == H1;

  // Per-lane weights as packed-fp16 pairs (1 VGPR each):
  // lane u<36 -> 4 rows of W_hh1; lane 36 -> 4 rows of W_ih2.
  float w2[4][18];
  float wB[4] = {0, 0, 0, 0}, bias[4] = {0, 0, 0, 0};
#pragma unroll
  for (int g = 0; g < 4; ++g)
#pragma unroll
    for (int k = 0; k < 18; ++k) w2[g][k] = 0.f;

  if (isA) {
#pragma unroll
    for (int g = 0; g < 4; ++g) {
      const int row = g * H1 + lane;
      const float* wr = Whh1 + row * H1;
#pragma unroll
      for (int k = 0; k < 18; ++k) w2[g][k] = pack2h(wr[2 * k], wr[2 * k + 1]);
      wB[g] = Wih1[row];
      bias[g] = bih1[row] + bhh1[row];
    }
  } else if (isL2) {
#pragma unroll
    for (int g = 0; g < 4; ++g) {
      const float* wr = Wih2 + g * H1;
#pragma unroll
      for (int k = 0; k < 18; ++k) w2[g][k] = pack2h(wr[2 * k], wr[2 * k + 1]);
      wB[g] = Whh2[g];  // multiplies h2_{t-1} (fp32)
      bias[g] = bih2[g] + bhh2[g];
    }
  }

  const float* xp = x + (size_t)batch * T_LEN;
  float* outp = out + (size_t)batch * T_LEN;
  const char* rd = (const char*)(isA ? hh : hr);  // A reads h; L2 reads relu(h)

  hh[lane] = (_Float16)0.f;  // h0 = 0 (own region; in-order LDS, no barrier)
  hr[lane] = (_Float16)0.f;
  __builtin_amdgcn_wave_barrier();

  float c = 0.f, hself = 0.f;
  float4 ov = make_float4(0.f, 0.f, 0.f, 0.f);

  auto substep = [&](float xv) {
    const float xin = isL2 ? hself : xv;  // L2's "input" is its own h2_{t-1}
    // 36 fp16 h values = 72 B: 4x b128 + 1x b64 (broadcast; <=2 addrs/wave).
    float f[18];
    const float4 q0 = *(const float4*)(rd);
    const float4 q1 = *(const float4*)(rd + 16);
    const float4 q2 = *(const float4*)(rd + 32);
    const float4 q3 = *(const float4*)(rd + 48);
    const float2 q4 = *(const float2*)(rd + 64);
    f[0] = q0.x;  f[1] = q0.y;  f[2] = q0.z;  f[3] = q0.w;
    f[4] = q1.x;  f[5] = q1.y;  f[6] = q1.z;  f[7] = q1.w;
    f[8] = q2.x;  f[9] = q2.y;  f[10] = q2.z; f[11] = q2.w;
    f[12] = q3.x; f[13] = q3.y; f[14] = q3.z; f[15] = q3.w;
    f[16] = q4.x; f[17] = q4.y;
    float a0 = fmaf(xin, wB[0], bias[0]);
    float a1 = fmaf(xin, wB[1], bias[1]);
    float a2 = fmaf(xin, wB[2], bias[2]);
    float a3 = fmaf(xin, wB[3], bias[3]);
#pragma unroll
    for (int k = 0; k < 18; ++k) {
      a0 = fdot2(w2[0][k], f[k], a0);
      a1 = fdot2(w2[1][k], f[k], a1);
      a2 = fdot2(w2[2][k], f[k], a2);
      a3 = fdot2(w2[3][k], f[k], a3);
    }
    const float I = sigm(a0), F = sigm(a1), G = tanh_fast(a2), O = sigm(a3);
    c = fmaf(F, c, I * G);
    hself = O * tanh_fast(c);
    __builtin_amdgcn_wave_barrier();
    hh[lane] = (_Float16)hself;            // lanes>=36 hit dump slots
    hr[lane] = (_Float16)fmaxf(hself, 0.f);
    __builtin_amdgcn_wave_barrier();
  };

  // Peeled iteration 0: A-lanes compute h1_0; L2 lane's result is pre-sequence
  // garbage -> reset its state and re-zero what the garbage step wrote.
  float4 qc = *(const float4*)xp;  // x[0..3]
  substep(qc.x);
  c = isL2 ? 0.f : c;
  hself = isL2 ? 0.f : hself;
  __builtin_amdgcn_wave_barrier();
  hh[lane] = isA ? (_Float16)hself : (_Float16)0.f;
  hr[lane] = isA ? (_Float16)fmaxf(hself, 0.f) : (_Float16)0.f;
  __builtin_amdgcn_wave_barrier();

  // Group m: iterations 4m+1 .. 4m+4.
  //   A-lane iteration t computes h1_t (uses x[t]).
  //   L2 lane iteration t computes out[t-1] (reads relu(h1_{t-1}), skew 1).
  // -> group m completes out[4m .. 4m+3].
  for (int t0 = 0; t0 < T_LEN; t0 += 4) {
    const int tn = (t0 + 8 <= T_LEN) ? (t0 + 4) : (T_LEN - 4);
    const float4 qn = *(const float4*)(xp + tn);
    substep(qc.y);
    ov.x = hself;
    substep(qc.z);
    ov.y = hself;
    substep(qc.w);
    ov.z = hself;
    substep(qn.x);  // t=4m+4; at t0=2044 feeds stale x, result discarded
    ov.w = hself;
    if (isL2) *(float4*)(outp + t0) = ov;
    qc = qn;
  }
}

}  // namespace

extern "C" void kernel_launch(void* const* d_in, const int* in_sizes, int n_in,
                              void* d_out, int out_size, void* d_ws, size_t ws_size,
                              hipStream_t stream) {
  const float* x    = (const float*)d_in[0];
  const float* Wih1 = (const float*)d_in[1];
  const float* Whh1 = (const float*)d_in[2];
  const float* bih1 = (const float*)d_in[3];
  const float* bhh1 = (const float*)d_in[4];
  const float* Wih2 = (const float*)d_in[5];
  const float* Whh2 = (const float*)d_in[6];
  const float* bih2 = (const float*)d_in[7];
  const float* bhh2 = (const float*)d_in[8];
  float* out = (float*)d_out;

  dim3 grid(B_TOT / WPB);  // 512 blocks; 2 blocks/CU -> 8 waves/CU, no barriers
  dim3 block(BLOCK);       // 256 threads = 4 autonomous waves (1 batch each)
  hipLaunchKernelGGL(lstm2_kernel, grid, block, 0, stream,
                     x, Wih1, Whh1, bih1, bhh1, Wih2, Whh2, bih2, bhh2, out);
}